// Round 12
// baseline (546.314 us; speedup 1.0000x reference)
//
#include <hip/hip_runtime.h>

typedef __attribute__((ext_vector_type(8))) short short8;
typedef __attribute__((ext_vector_type(4))) float f32x4;

constexpr int NB  = 32;
constexpr int NS  = 1024;
constexpr int ND  = 256;
constexpr int NH  = 8;
constexpr int NDH = 32;
constexpr int NF  = 512;
constexpr int NM  = NB * NS;          // 32768 rows
#define RSD 0.17677669529663687f       // 1/sqrt(32)

static __device__ __forceinline__ ushort f2bf(float f) {
    union { float f; unsigned u; } v; v.f = f;
    unsigned r = v.u + 0x7fffu + ((v.u >> 16) & 1u);   // round-to-nearest-even
    return (ushort)(r >> 16);
}
static __device__ __forceinline__ float bf2f(ushort u) {
    union { unsigned u; float f; } v; v.u = (unsigned)u << 16; return v.f;
}

// ---------------------------------------------------------------------------
// fp32 -> bf16 hi only (x: the lo term is dropped in QKV, err ~2^-9).
// ---------------------------------------------------------------------------
__global__ __launch_bounds__(256) void split_hi(
    const float* __restrict__ in, ushort* __restrict__ hi, int n4)
{
    int i = blockIdx.x * 256 + threadIdx.x;
    if (i >= n4) return;
    float4 v = ((const float4*)in)[i];
    ushort4 h;
    h.x = f2bf(v.x); h.y = f2bf(v.y); h.z = f2bf(v.z); h.w = f2bf(v.w);
    ((ushort4*)hi)[i] = h;
}

// ---------------------------------------------------------------------------
// All six weight splits in one launch. grid=(128, 6).
// ---------------------------------------------------------------------------
__global__ __launch_bounds__(256) void split_weights(
    const float* __restrict__ Wq, const float* __restrict__ Wk,
    const float* __restrict__ Wv, const float* __restrict__ Wo,
    const float* __restrict__ W1, const float* __restrict__ W2,
    ushort* __restrict__ whi, ushort* __restrict__ wlo)
{
    const int seg = blockIdx.y;
    const float* src;
    size_t off;
    int n4;
    switch (seg) {
        case 0: src = Wq; off = 0;      n4 = 16384; break;
        case 1: src = Wk; off = 65536;  n4 = 16384; break;
        case 2: src = Wv; off = 131072; n4 = 16384; break;
        case 3: src = Wo; off = 196608; n4 = 16384; break;
        case 4: src = W1; off = 262144; n4 = 32768; break;
        default: src = W2; off = 393216; n4 = 32768; break;
    }
    int i = blockIdx.x * 256 + threadIdx.x;
    if (i >= n4) return;
    float4 v = ((const float4*)src)[i];
    ushort4 h, l;
    h.x = f2bf(v.x); l.x = f2bf(v.x - bf2f(h.x));
    h.y = f2bf(v.y); l.y = f2bf(v.y - bf2f(h.y));
    h.z = f2bf(v.z); l.z = f2bf(v.z - bf2f(h.z));
    h.w = f2bf(v.w); l.w = f2bf(v.w - bf2f(h.w));
    ((ushort4*)(whi + off))[i] = h;
    ((ushort4*)(wlo + off))[i] = l;
}

// ---------------------------------------------------------------------------
// MFMA GEMM core: 128x128 tile, BK=64 (halved barrier count vs BK=32),
// 4 waves (2x2, 64x64 each), reg-pipelined prefetch.
// Stride 72 ushorts: ds_write starts (row*36+half*16+slot*4)%32 uniform ->
// minimum aliasing; ds_read starts 4*(row+quad)%32 -> 8 groups = minimum.
// TERMS_==3: AhBh + AhBl + AlBh; TERMS_==2: A-hi only (AhBh + AhBl).
// ---------------------------------------------------------------------------
#define GEMM_CORE(K_, TERMS_)                                                  \
    __shared__ ushort sAh[128 * 72];                                           \
    __shared__ ushort sAl[(TERMS_ == 3) ? 128 * 72 : 8];                       \
    __shared__ ushort sBh[128 * 72];                                           \
    __shared__ ushort sBl[128 * 72];                                           \
    const int t = threadIdx.x;                                                 \
    const int w = t >> 6, ln = t & 63;                                         \
    const int wr = w >> 1, wc = w & 1;                                         \
    const int col = ln & 15, quad = ln >> 4;                                   \
    const int srow = t >> 1, skb = (t & 1) << 5;                               \
    const ushort* gAh = Ahi + (size_t)(rbase + srow) * (K_) + skb;             \
    const ushort* gAl = (TERMS_ == 3) ? Alo + (size_t)(rbase + srow) * (K_) + skb : gAh; \
    const ushort* gBh = Whi + (size_t)(jbase + srow) * (K_) + skb;             \
    const ushort* gBl = Wlo + (size_t)(jbase + srow) * (K_) + skb;             \
    ushort* wAh = &sAh[srow * 72 + skb];                                       \
    ushort* wAl = (TERMS_ == 3) ? &sAl[srow * 72 + skb] : wAh;                 \
    ushort* wBh = &sBh[srow * 72 + skb];                                       \
    ushort* wBl = &sBl[srow * 72 + skb];                                       \
    f32x4 acc[4][4] = {};                                                      \
    short8 a0, a1, a2, a3, b0, b1, b2, b3, d0, d1, d2, d3;                     \
    short8 c0 = {}, c1 = {}, c2 = {}, c3 = {};                                 \
    a0 = *(const short8*)(gAh);      a1 = *(const short8*)(gAh + 8);           \
    a2 = *(const short8*)(gAh + 16); a3 = *(const short8*)(gAh + 24);          \
    if (TERMS_ == 3) {                                                         \
        c0 = *(const short8*)(gAl);      c1 = *(const short8*)(gAl + 8);       \
        c2 = *(const short8*)(gAl + 16); c3 = *(const short8*)(gAl + 24);      \
    }                                                                          \
    b0 = *(const short8*)(gBh);      b1 = *(const short8*)(gBh + 8);           \
    b2 = *(const short8*)(gBh + 16); b3 = *(const short8*)(gBh + 24);          \
    d0 = *(const short8*)(gBl);      d1 = *(const short8*)(gBl + 8);           \
    d2 = *(const short8*)(gBl + 16); d3 = *(const short8*)(gBl + 24);          \
    for (int k0 = 0; k0 < (K_); k0 += 64) {                                    \
        __syncthreads();                                                       \
        *(short8*)wAh = a0;        *(short8*)(wAh + 8) = a1;                   \
        *(short8*)(wAh + 16) = a2; *(short8*)(wAh + 24) = a3;                  \
        if (TERMS_ == 3) {                                                     \
            *(short8*)wAl = c0;        *(short8*)(wAl + 8) = c1;               \
            *(short8*)(wAl + 16) = c2; *(short8*)(wAl + 24) = c3;              \
        }                                                                      \
        *(short8*)wBh = b0;        *(short8*)(wBh + 8) = b1;                   \
        *(short8*)(wBh + 16) = b2; *(short8*)(wBh + 24) = b3;                  \
        *(short8*)wBl = d0;        *(short8*)(wBl + 8) = d1;                   \
        *(short8*)(wBl + 16) = d2; *(short8*)(wBl + 24) = d3;                  \
        __syncthreads();                                                       \
        if (k0 + 64 < (K_)) {                                                  \
            a0 = *(const short8*)(gAh + k0 + 64);                              \
            a1 = *(const short8*)(gAh + k0 + 72);                              \
            a2 = *(const short8*)(gAh + k0 + 80);                              \
            a3 = *(const short8*)(gAh + k0 + 88);                              \
            if (TERMS_ == 3) {                                                 \
                c0 = *(const short8*)(gAl + k0 + 64);                          \
                c1 = *(const short8*)(gAl + k0 + 72);                          \
                c2 = *(const short8*)(gAl + k0 + 80);                          \
                c3 = *(const short8*)(gAl + k0 + 88);                          \
            }                                                                  \
            b0 = *(const short8*)(gBh + k0 + 64);                              \
            b1 = *(const short8*)(gBh + k0 + 72);                              \
            b2 = *(const short8*)(gBh + k0 + 80);                              \
            b3 = *(const short8*)(gBh + k0 + 88);                              \
            d0 = *(const short8*)(gBl + k0 + 64);                              \
            d1 = *(const short8*)(gBl + k0 + 72);                              \
            d2 = *(const short8*)(gBl + k0 + 80);                              \
            d3 = *(const short8*)(gBl + k0 + 88);                              \
        }                                                                      \
        _Pragma("unroll")                                                      \
        for (int ks = 0; ks < 2; ++ks) {                                       \
            short8 af[4], afl[4], bfv[4], bfl[4];                              \
            _Pragma("unroll")                                                  \
            for (int m = 0; m < 4; ++m) {                                      \
                const int ra = (wr * 64 + m * 16 + col) * 72 + ks * 32 + quad * 8; \
                const int rb = (wc * 64 + m * 16 + col) * 72 + ks * 32 + quad * 8; \
                af[m]  = *(const short8*)&sAh[ra];                             \
                if (TERMS_ == 3) afl[m] = *(const short8*)&sAl[ra];            \
                bfv[m] = *(const short8*)&sBh[rb];                             \
                bfl[m] = *(const short8*)&sBl[rb];                             \
            }                                                                  \
            _Pragma("unroll")                                                  \
            for (int m = 0; m < 4; ++m)                                        \
                _Pragma("unroll")                                              \
                for (int n = 0; n < 4; ++n) {                                  \
                    acc[m][n] = __builtin_amdgcn_mfma_f32_16x16x32_bf16(af[m],  bfv[n], acc[m][n], 0, 0, 0); \
                    acc[m][n] = __builtin_amdgcn_mfma_f32_16x16x32_bf16(af[m],  bfl[n], acc[m][n], 0, 0, 0); \
                    if (TERMS_ == 3)                                           \
                        acc[m][n] = __builtin_amdgcn_mfma_f32_16x16x32_bf16(afl[m], bfv[n], acc[m][n], 0, 0, 0); \
                }                                                              \
        }                                                                      \
    }

// ---------------------------------------------------------------------------
// Generic MFMA GEMM: out = epi(A @ W.T + bias).
// epi 0: outf = 2*v (O-proj); 1: ohi = hi(relu(v)); 2: outf += v.
// ---------------------------------------------------------------------------
template<int TERMS>
__global__ __launch_bounds__(256, 2) void gemm_mfma(
    const ushort* __restrict__ Ahi, const ushort* __restrict__ Alo,
    const ushort* __restrict__ Whi, const ushort* __restrict__ Wlo,
    const float* __restrict__ bias,
    float* __restrict__ outf, ushort* __restrict__ ohi,
    int N, int K, int epi)
{
    const int rbase = blockIdx.y << 7;
    const int jbase = blockIdx.x << 7;
    GEMM_CORE(K, TERMS)

    #pragma unroll
    for (int n = 0; n < 4; ++n) {
        const int cg = jbase + wc * 64 + n * 16 + col;
        const float bs = bias[cg];
        #pragma unroll
        for (int m = 0; m < 4; ++m) {
            #pragma unroll
            for (int r = 0; r < 4; ++r) {
                const int row = rbase + wr * 64 + m * 16 + quad * 4 + r;
                float v = acc[m][n][r] + bs;
                size_t oidx = (size_t)row * N + cg;
                if (epi == 0) {
                    outf[oidx] = 2.f * v;
                } else if (epi == 1) {
                    ohi[oidx] = f2bf(fmaxf(v, 0.f));
                } else {
                    outf[oidx] += v;
                }
            }
        }
    }
}

// ---------------------------------------------------------------------------
// QKV MFMA GEMM (2-term: x-hi only). z=0 -> q=(acc+b+hidden)*RSD split;
// z=1 -> k split; z=2 -> v fp32. Output scattered to [B,H,S,32].
// ---------------------------------------------------------------------------
__global__ __launch_bounds__(256, 2) void gemm_qkv_mfma(
    const ushort* __restrict__ xhi,
    const ushort* __restrict__ whi, const ushort* __restrict__ wlo,
    const float* __restrict__ bq, const float* __restrict__ bk, const float* __restrict__ bv,
    const float* __restrict__ hidden,
    ushort* __restrict__ qhi, ushort* __restrict__ qlo,
    ushort* __restrict__ khi, ushort* __restrict__ klo,
    float* __restrict__ vb)
{
    const int z = blockIdx.z;
    const int rbase = blockIdx.y << 7;
    const int jbase = blockIdx.x << 7;
    const ushort* Ahi = xhi;
    const ushort* Alo = xhi;   // unused (TERMS=2)
    const ushort* Whi = whi + (size_t)z * 65536;
    const ushort* Wlo = wlo + (size_t)z * 65536;
    const float* bias = (z == 0) ? bq : (z == 1) ? bk : bv;
    GEMM_CORE(ND, 2)

    #pragma unroll
    for (int n = 0; n < 4; ++n) {
        const int cg = jbase + wc * 64 + n * 16 + col;
        const float bs = bias[cg];
        const int hh = cg >> 5, dd = cg & 31;
        #pragma unroll
        for (int m = 0; m < 4; ++m) {
            #pragma unroll
            for (int r = 0; r < 4; ++r) {
                const int row = rbase + wr * 64 + m * 16 + quad * 4 + r;
                const int b_i = row >> 10, s_i = row & 1023;
                size_t idx = (((size_t)(b_i * NH + hh)) * NS + s_i) * NDH + dd;
                float v = acc[m][n][r] + bs;
                if (z == 2) {
                    vb[idx] = v;
                } else if (z == 0) {
                    v = (v + hidden[idx]) * RSD;
                    ushort h = f2bf(v);
                    qhi[idx] = h;
                    qlo[idx] = f2bf(v - bf2f(h));
                } else {
                    ushort h = f2bf(v);
                    khi[idx] = h;
                    klo[idx] = f2bf(v - bf2f(h));
                }
            }
        }
    }
}

// ---------------------------------------------------------------------------
// Flash-fused attention (R10-measured). Block = 4 waves = 64 q-rows of one bh.
// ---------------------------------------------------------------------------
constexpr int VS  = 136;
constexpr int PST = 136;
__global__ __launch_bounds__(256, 4) void attn_flash(
    const ushort* __restrict__ qhi, const ushort* __restrict__ qlo,
    const ushort* __restrict__ khi, const ushort* __restrict__ klo,
    const float* __restrict__ vb,
    float* __restrict__ attn, ushort* __restrict__ cthi, ushort* __restrict__ ctlo)
{
    __shared__ ushort Vthi[32 * VS];
    __shared__ ushort Vtlo[32 * VS];
    __shared__ ushort Ps[4][16 * PST];
    const int bid = blockIdx.x;
    const int lid = (bid & 7) * 512 + (bid >> 3);   // 4096 % 8 == 0: bijective
    const int qt = lid & 15, bh = lid >> 4;
    const int q0 = qt << 6;
    const int t = threadIdx.x;
    const int w = t >> 6, ln = t & 63;
    const int col = ln & 15, quad = ln >> 4;
    const int qr0 = q0 + 16 * w;
    ushort* myP = Ps[w];

    const size_t bhbase = (size_t)bh * NS * NDH;
    const size_t aoff = bhbase + (size_t)(qr0 + col) * NDH + quad * 8;
    const short8 ahi = *(const short8*)(qhi + aoff);
    const short8 alo = *(const short8*)(qlo + aoff);

    const float* vbase = vb + bhbase;
    const int sdd = t & 31, skg = (t >> 5) << 4;

    f32x4 acc0 = {0.f, 0.f, 0.f, 0.f}, acc1 = {0.f, 0.f, 0.f, 0.f};
    float S[4] = {0.f, 0.f, 0.f, 0.f};

    // ================= Pass 1 =================
    for (int k0 = 0; k0 < NS; k0 += 128) {
        __syncthreads();
        ushort hs[16], ls[16];
        #pragma unroll
        for (int c = 0; c < 16; ++c) {
            float xx = vbase[(size_t)(k0 + skg + c) * NDH + sdd];
            ushort h = f2bf(xx);
            hs[c] = h; ls[c] = f2bf(xx - bf2f(h));
        }
        #pragma unroll
        for (int c4 = 0; c4 < 4; ++c4) {
            ushort4 hv = make_ushort4(hs[c4 * 4], hs[c4 * 4 + 1], hs[c4 * 4 + 2], hs[c4 * 4 + 3]);
            ushort4 lv = make_ushort4(ls[c4 * 4], ls[c4 * 4 + 1], ls[c4 * 4 + 2], ls[c4 * 4 + 3]);
            *(ushort4*)&Vthi[sdd * VS + skg + c4 * 4] = hv;
            *(ushort4*)&Vtlo[sdd * VS + skg + c4 * 4] = lv;
        }
        __syncthreads();

        #pragma unroll
        for (int tl = 0; tl < 8; ++tl) {
            const int kk = k0 + tl * 16;
            const size_t boff = bhbase + (size_t)(kk + col) * NDH + quad * 8;
            short8 bhi = *(const short8*)(khi + boff);
            short8 blo = *(const short8*)(klo + boff);
            f32x4 c = {0.f, 0.f, 0.f, 0.f};
            c = __builtin_amdgcn_mfma_f32_16x16x32_bf16(ahi, bhi, c, 0, 0, 0);
            c = __builtin_amdgcn_mfma_f32_16x16x32_bf16(ahi, blo, c, 0, 0, 0);
            c = __builtin_amdgcn_mfma_f32_16x16x32_bf16(alo, bhi, c, 0, 0, 0);
            #pragma unroll
            for (int r = 0; r < 4; ++r) {
                float e = __expf(c[r]);
                S[r] += e;
                myP[(quad * 4 + r) * PST + tl * 16 + col] = f2bf(e);
            }
        }

        #pragma unroll
        for (int sl = 0; sl < 4; ++sl) {
            const int kl = sl * 32 + quad * 8;
            short8 pa = *(const short8*)&myP[col * PST + kl];
            short8 bhi0 = *(const short8*)&Vthi[col * VS + kl];
            short8 blo0 = *(const short8*)&Vtlo[col * VS + kl];
            short8 bhi1 = *(const short8*)&Vthi[(16 + col) * VS + kl];
            short8 blo1 = *(const short8*)&Vtlo[(16 + col) * VS + kl];
            acc0 = __builtin_amdgcn_mfma_f32_16x16x32_bf16(pa, bhi0, acc0, 0, 0, 0);
            acc0 = __builtin_amdgcn_mfma_f32_16x16x32_bf16(pa, blo0, acc0, 0, 0, 0);
            acc1 = __builtin_amdgcn_mfma_f32_16x16x32_bf16(pa, bhi1, acc1, 0, 0, 0);
            acc1 = __builtin_amdgcn_mfma_f32_16x16x32_bf16(pa, blo1, acc1, 0, 0, 0);
        }
    }

    float inv[4];
    #pragma unroll
    for (int r = 0; r < 4; ++r) {
        float s = S[r];
        #pragma unroll
        for (int m = 8; m >= 1; m >>= 1) s += __shfl_xor(s, m, 64);
        inv[r] = 1.f / s;
    }

    const int b_i = bh >> 3, hh = bh & 7;
    const int qrow = qr0 + quad * 4;
    #pragma unroll
    for (int r = 0; r < 4; ++r) {
        size_t base = ((size_t)b_i * NS + qrow + r) * ND + hh * NDH;
        float v0 = acc0[r] * inv[r], v1 = acc1[r] * inv[r];
        ushort h0 = f2bf(v0), h1 = f2bf(v1);
        cthi[base + col]      = h0;
        ctlo[base + col]      = f2bf(v0 - bf2f(h0));
        cthi[base + 16 + col] = h1;
        ctlo[base + 16 + col] = f2bf(v1 - bf2f(h1));
    }

    // ================= Pass 2: attn output =================
    float* abase = attn + ((size_t)bh * NS + qrow) * NS;
    #pragma unroll 4
    for (int tl = 0; tl < 64; ++tl) {
        const int kk = tl * 16;
        const size_t boff = bhbase + (size_t)(kk + col) * NDH + quad * 8;
        short8 bhi = *(const short8*)(khi + boff);
        short8 blo = *(const short8*)(klo + boff);
        f32x4 c = {0.f, 0.f, 0.f, 0.f};
        c = __builtin_amdgcn_mfma_f32_16x16x32_bf16(ahi, bhi, c, 0, 0, 0);
        c = __builtin_amdgcn_mfma_f32_16x16x32_bf16(ahi, blo, c, 0, 0, 0);
        c = __builtin_amdgcn_mfma_f32_16x16x32_bf16(alo, bhi, c, 0, 0, 0);
        #pragma unroll
        for (int r = 0; r < 4; ++r) {
            float p = __expf(c[r]) * inv[r];
            __builtin_nontemporal_store(p, &abase[(size_t)r * NS + kk + col]);
        }
    }
}

// ---------------------------------------------------------------------------
// LayerNorm: ln_split -> bf16 hi only (FFN1 is 2-term); ln_final -> x + LN(x).
// ---------------------------------------------------------------------------
__global__ __launch_bounds__(256) void ln_split(
    const float* __restrict__ x, const float* __restrict__ g,
    const float* __restrict__ be, ushort* __restrict__ ohi)
{
    const int t = threadIdx.x;
    const int wave = t >> 6, lane = t & 63;
    const int row = (blockIdx.x << 2) + wave;
    const float* xr = x + (size_t)row * ND;
    float4 v = *(const float4*)&xr[lane << 2];
    float s = v.x + v.y + v.z + v.w;
    #pragma unroll
    for (int m = 32; m >= 1; m >>= 1) s += __shfl_xor(s, m, 64);
    float mu = s * (1.f / 256.f);
    float dx = v.x - mu, dy = v.y - mu, dz = v.z - mu, dw = v.w - mu;
    float s2 = dx * dx + dy * dy + dz * dz + dw * dw;
    #pragma unroll
    for (int m = 32; m >= 1; m >>= 1) s2 += __shfl_xor(s2, m, 64);
    float rs = rsqrtf(s2 * (1.f / 256.f) + 1e-5f);
    float4 gv = *(const float4*)&g[lane << 2];
    float4 bv = *(const float4*)&be[lane << 2];
    ushort4 h;
    h.x = f2bf(dx * rs * gv.x + bv.x);
    h.y = f2bf(dy * rs * gv.y + bv.y);
    h.z = f2bf(dz * rs * gv.z + bv.z);
    h.w = f2bf(dw * rs * gv.w + bv.w);
    ((ushort4*)ohi)[((size_t)row * ND + (lane << 2)) >> 2] = h;
}

__global__ __launch_bounds__(256) void ln_final(
    const float* __restrict__ x, const float* __restrict__ g,
    const float* __restrict__ be, float* __restrict__ out)
{
    const int t = threadIdx.x;
    const int wave = t >> 6, lane = t & 63;
    const int row = (blockIdx.x << 2) + wave;
    const float* xr = x + (size_t)row * ND;
    float4 v = *(const float4*)&xr[lane << 2];
    float s = v.x + v.y + v.z + v.w;
    #pragma unroll
    for (int m = 32; m >= 1; m >>= 1) s += __shfl_xor(s, m, 64);
    float mu = s * (1.f / 256.f);
    float dx = v.x - mu, dy = v.y - mu, dz = v.z - mu, dw = v.w - mu;
    float s2 = dx * dx + dy * dy + dz * dz + dw * dw;
    #pragma unroll
    for (int m = 32; m >= 1; m >>= 1) s2 += __shfl_xor(s2, m, 64);
    float rs = rsqrtf(s2 * (1.f / 256.f) + 1e-5f);
    float4 gv = *(const float4*)&g[lane << 2];
    float4 bv = *(const float4*)&be[lane << 2];
    float4 o;
    o.x = dx * rs * gv.x + bv.x + v.x;
    o.y = dy * rs * gv.y + bv.y + v.y;
    o.z = dz * rs * gv.z + bv.z + v.z;
    o.w = dw * rs * gv.w + bv.w + v.w;
    *(float4*)&out[(size_t)row * ND + (lane << 2)] = o;
}

// ---------------------------------------------------------------------------
extern "C" void kernel_launch(void* const* d_in, const int* in_sizes, int n_in,
                              void* d_out, int out_size, void* d_ws, size_t ws_size,
                              hipStream_t stream)
{
    const float* x      = (const float*)d_in[0];
    const float* hidden = (const float*)d_in[1];
    const float* Wq = (const float*)d_in[2];
    const float* bq = (const float*)d_in[3];
    const float* Wk = (const float*)d_in[4];
    const float* bk = (const float*)d_in[5];
    const float* Wv = (const float*)d_in[6];
    const float* bv = (const float*)d_in[7];
    const float* Wo = (const float*)d_in[8];
    const float* bo = (const float*)d_in[9];
    const float* g1  = (const float*)d_in[10];
    const float* be1 = (const float*)d_in[11];
    const float* g2  = (const float*)d_in[12];
    const float* be2 = (const float*)d_in[13];
    const float* W1 = (const float*)d_in[14];
    const float* b1 = (const float*)d_in[15];
    const float* W2 = (const float*)d_in[16];
    const float* b2 = (const float*)d_in[17];

    float* out  = (float*)d_out;
    float* attn = out + (size_t)NM * ND;

    float* ws = (float*)d_ws;
    ushort* xhi  = (ushort*)ws;
    ushort* qhi  = (ushort*)(ws + 8388608);
    ushort* qlo  = (ushort*)(ws + 12582912);
    ushort* khi  = (ushort*)(ws + 16777216);
    ushort* klo  = (ushort*)(ws + 20971520);
    float*  vbuf = ws + 25165824;                 // fp32 [B,H,S,32]
    ushort* cthi = (ushort*)ws;                   // reuse x region
    ushort* ctlo = (ushort*)(ws + 4194304);
    float*  hbuf = ws + 33554432;                 // fp32 [M,256]
    ushort* hnhi = (ushort*)(ws + 8388608);       // reuse q region
    ushort* ffhi = (ushort*)(ws + 16777216);      // reuse k region
    ushort* whi  = (ushort*)(ws + 41943040);
    ushort* wlo  = (ushort*)(ws + 42205184);

    split_weights<<<dim3(128, 6), 256, 0, stream>>>(Wq, Wk, Wv, Wo, W1, W2, whi, wlo);
    split_hi<<<8192, 256, 0, stream>>>(x, xhi, 2097152);

    // 1. QKV projections (2-term: x-hi only)
    gemm_qkv_mfma<<<dim3(2, 256, 3), 256, 0, stream>>>(
        xhi, whi, wlo, bq, bk, bv, hidden, qhi, qlo, khi, klo, vbuf);
    // 2+3. flash-fused scores+softmax+PV; writes attn + ctx
    attn_flash<<<dim3(4096), 256, 0, stream>>>(
        qhi, qlo, khi, klo, vbuf, attn, cthi, ctlo);
    // 4. h = 2*(ctx @ Wo.T + bo)  (3-term guard on the signal path)
    gemm_mfma<3><<<dim3(2, 256), 256, 0, stream>>>(
        cthi, ctlo, whi + 196608, wlo + 196608, bo, hbuf, nullptr, ND, ND, 0);
    // 5. hn = LN1(h) -> bf16 hi only
    ln_split<<<NM / 4, 256, 0, stream>>>(hbuf, g1, be1, hnhi);
    // 6. ff = relu(hn @ W1.T + b1) -> bf16 hi only (2-term)
    gemm_mfma<2><<<dim3(4, 256), 256, 0, stream>>>(
        hnhi, nullptr, whi + 262144, wlo + 262144, b1, nullptr, ffhi, NF, ND, 1);
    // 7. h += ff @ W2.T + b2 (2-term)
    gemm_mfma<2><<<dim3(2, 256), 256, 0, stream>>>(
        ffhi, nullptr, whi + 393216, wlo + 393216, b2, hbuf, nullptr, ND, NF, 2);
    // 8. out = h + LN2(h)
    ln_final<<<NM / 4, 256, 0, stream>>>(hbuf, g2, be2, out);
}

// Round 13
// 525.274 us; speedup vs baseline: 1.0401x; 1.0401x over previous
//
#include <hip/hip_runtime.h>

typedef __attribute__((ext_vector_type(8))) short short8;
typedef __attribute__((ext_vector_type(4))) float f32x4;

constexpr int NB  = 32;
constexpr int NS  = 1024;
constexpr int ND  = 256;
constexpr int NH  = 8;
constexpr int NDH = 32;
constexpr int NF  = 512;
constexpr int NM  = NB * NS;          // 32768 rows
#define RSD 0.17677669529663687f       // 1/sqrt(32)

static __device__ __forceinline__ ushort f2bf(float f) {
    union { float f; unsigned u; } v; v.f = f;
    unsigned r = v.u + 0x7fffu + ((v.u >> 16) & 1u);   // round-to-nearest-even
    return (ushort)(r >> 16);
}
static __device__ __forceinline__ float bf2f(ushort u) {
    union { unsigned u; float f; } v; v.u = (unsigned)u << 16; return v.f;
}

// ---------------------------------------------------------------------------
// fp32 -> bf16 hi only (x: the lo term is dropped in QKV, err ~2^-9).
// ---------------------------------------------------------------------------
__global__ __launch_bounds__(256) void split_hi(
    const float* __restrict__ in, ushort* __restrict__ hi, int n4)
{
    int i = blockIdx.x * 256 + threadIdx.x;
    if (i >= n4) return;
    float4 v = ((const float4*)in)[i];
    ushort4 h;
    h.x = f2bf(v.x); h.y = f2bf(v.y); h.z = f2bf(v.z); h.w = f2bf(v.w);
    ((ushort4*)hi)[i] = h;
}

// ---------------------------------------------------------------------------
// All six weight splits in one launch. grid=(128, 6).
// ---------------------------------------------------------------------------
__global__ __launch_bounds__(256) void split_weights(
    const float* __restrict__ Wq, const float* __restrict__ Wk,
    const float* __restrict__ Wv, const float* __restrict__ Wo,
    const float* __restrict__ W1, const float* __restrict__ W2,
    ushort* __restrict__ whi, ushort* __restrict__ wlo)
{
    const int seg = blockIdx.y;
    const float* src;
    size_t off;
    int n4;
    switch (seg) {
        case 0: src = Wq; off = 0;      n4 = 16384; break;
        case 1: src = Wk; off = 65536;  n4 = 16384; break;
        case 2: src = Wv; off = 131072; n4 = 16384; break;
        case 3: src = Wo; off = 196608; n4 = 16384; break;
        case 4: src = W1; off = 262144; n4 = 32768; break;
        default: src = W2; off = 393216; n4 = 32768; break;
    }
    int i = blockIdx.x * 256 + threadIdx.x;
    if (i >= n4) return;
    float4 v = ((const float4*)src)[i];
    ushort4 h, l;
    h.x = f2bf(v.x); l.x = f2bf(v.x - bf2f(h.x));
    h.y = f2bf(v.y); l.y = f2bf(v.y - bf2f(h.y));
    h.z = f2bf(v.z); l.z = f2bf(v.z - bf2f(h.z));
    h.w = f2bf(v.w); l.w = f2bf(v.w - bf2f(h.w));
    ((ushort4*)(whi + off))[i] = h;
    ((ushort4*)(wlo + off))[i] = l;
}

// ---------------------------------------------------------------------------
// MFMA GEMM core (R11-measured): 128x128 tile, BK=32, 4 waves (2x2), pipelined.
// TERMS_==3: AhBh + AhBl + AlBh; TERMS_==2: A-hi only (AhBh + AhBl).
// ---------------------------------------------------------------------------
#define GEMM_CORE(K_, TERMS_)                                                  \
    __shared__ ushort sAh[128 * 40], sAl[128 * 40];                            \
    __shared__ ushort sBh[128 * 40], sBl[128 * 40];                            \
    const int t = threadIdx.x;                                                 \
    const int w = t >> 6, ln = t & 63;                                         \
    const int wr = w >> 1, wc = w & 1;                                         \
    const int col = ln & 15, quad = ln >> 4;                                   \
    const int srow = t >> 1, skb = (t & 1) << 4;                               \
    const ushort* gAh = Ahi + (size_t)(rbase + srow) * (K_) + skb;             \
    const ushort* gAl = (TERMS_ == 3) ? Alo + (size_t)(rbase + srow) * (K_) + skb : gAh; \
    const ushort* gBh = Whi + (size_t)(jbase + srow) * (K_) + skb;             \
    const ushort* gBl = Wlo + (size_t)(jbase + srow) * (K_) + skb;             \
    ushort* wAh = &sAh[srow * 40 + skb];                                       \
    ushort* wAl = &sAl[srow * 40 + skb];                                       \
    ushort* wBh = &sBh[srow * 40 + skb];                                       \
    ushort* wBl = &sBl[srow * 40 + skb];                                       \
    f32x4 acc[4][4] = {};                                                      \
    short8 a0 = *(const short8*)(gAh);                                         \
    short8 a1 = *(const short8*)(gAh + 8);                                     \
    short8 c0 = {}, c1 = {};                                                   \
    if (TERMS_ == 3) { c0 = *(const short8*)(gAl); c1 = *(const short8*)(gAl + 8); } \
    short8 b0 = *(const short8*)(gBh);                                         \
    short8 b1 = *(const short8*)(gBh + 8);                                     \
    short8 d0 = *(const short8*)(gBl);                                         \
    short8 d1 = *(const short8*)(gBl + 8);                                     \
    for (int k0 = 0; k0 < (K_); k0 += 32) {                                    \
        __syncthreads();                                                       \
        *(short8*)wAh = a0; *(short8*)(wAh + 8) = a1;                          \
        if (TERMS_ == 3) { *(short8*)wAl = c0; *(short8*)(wAl + 8) = c1; }     \
        *(short8*)wBh = b0; *(short8*)(wBh + 8) = b1;                          \
        *(short8*)wBl = d0; *(short8*)(wBl + 8) = d1;                          \
        __syncthreads();                                                       \
        if (k0 + 32 < (K_)) {                                                  \
            a0 = *(const short8*)(gAh + k0 + 32);                              \
            a1 = *(const short8*)(gAh + k0 + 40);                              \
            if (TERMS_ == 3) {                                                 \
                c0 = *(const short8*)(gAl + k0 + 32);                          \
                c1 = *(const short8*)(gAl + k0 + 40);                          \
            }                                                                  \
            b0 = *(const short8*)(gBh + k0 + 32);                              \
            b1 = *(const short8*)(gBh + k0 + 40);                              \
            d0 = *(const short8*)(gBl + k0 + 32);                              \
            d1 = *(const short8*)(gBl + k0 + 40);                              \
        }                                                                      \
        short8 af[4], afl[4], bfv[4], bfl[4];                                  \
        _Pragma("unroll")                                                      \
        for (int m = 0; m < 4; ++m) {                                          \
            af[m]  = *(const short8*)&sAh[(wr * 64 + m * 16 + col) * 40 + quad * 8]; \
            if (TERMS_ == 3)                                                   \
                afl[m] = *(const short8*)&sAl[(wr * 64 + m * 16 + col) * 40 + quad * 8]; \
            bfv[m] = *(const short8*)&sBh[(wc * 64 + m * 16 + col) * 40 + quad * 8]; \
            bfl[m] = *(const short8*)&sBl[(wc * 64 + m * 16 + col) * 40 + quad * 8]; \
        }                                                                      \
        _Pragma("unroll")                                                      \
        for (int m = 0; m < 4; ++m)                                            \
            _Pragma("unroll")                                                  \
            for (int n = 0; n < 4; ++n) {                                      \
                acc[m][n] = __builtin_amdgcn_mfma_f32_16x16x32_bf16(af[m],  bfv[n], acc[m][n], 0, 0, 0); \
                acc[m][n] = __builtin_amdgcn_mfma_f32_16x16x32_bf16(af[m],  bfl[n], acc[m][n], 0, 0, 0); \
                if (TERMS_ == 3)                                               \
                    acc[m][n] = __builtin_amdgcn_mfma_f32_16x16x32_bf16(afl[m], bfv[n], acc[m][n], 0, 0, 0); \
            }                                                                  \
    }

// ---------------------------------------------------------------------------
// Generic MFMA GEMM (used for FFN1): out = epi(A @ W.T + bias).
// epi 1: ohi = hi(relu(v)).
// ---------------------------------------------------------------------------
template<int TERMS>
__global__ __launch_bounds__(256, 2) void gemm_mfma(
    const ushort* __restrict__ Ahi, const ushort* __restrict__ Alo,
    const ushort* __restrict__ Whi, const ushort* __restrict__ Wlo,
    const float* __restrict__ bias,
    float* __restrict__ outf, ushort* __restrict__ ohi,
    int N, int K, int epi)
{
    const int rbase = blockIdx.y << 7;
    const int jbase = blockIdx.x << 7;
    GEMM_CORE(K, TERMS)

    #pragma unroll
    for (int n = 0; n < 4; ++n) {
        const int cg = jbase + wc * 64 + n * 16 + col;
        const float bs = bias[cg];
        #pragma unroll
        for (int m = 0; m < 4; ++m) {
            #pragma unroll
            for (int r = 0; r < 4; ++r) {
                const int row = rbase + wr * 64 + m * 16 + quad * 4 + r;
                float v = acc[m][n][r] + bs;
                size_t oidx = (size_t)row * N + cg;
                if (epi == 0) {
                    outf[oidx] = 2.f * v;
                } else if (epi == 1) {
                    ohi[oidx] = f2bf(fmaxf(v, 0.f));
                } else {
                    outf[oidx] += v;
                }
            }
        }
    }
}

// ---------------------------------------------------------------------------
// QKV MFMA GEMM (2-term: x-hi only). z=0 -> q=(acc+b+hidden)*RSD split;
// z=1 -> k split; z=2 -> v fp32. Output scattered to [B,H,S,32].
// ---------------------------------------------------------------------------
__global__ __launch_bounds__(256, 2) void gemm_qkv_mfma(
    const ushort* __restrict__ xhi,
    const ushort* __restrict__ whi, const ushort* __restrict__ wlo,
    const float* __restrict__ bq, const float* __restrict__ bk, const float* __restrict__ bv,
    const float* __restrict__ hidden,
    ushort* __restrict__ qhi, ushort* __restrict__ qlo,
    ushort* __restrict__ khi, ushort* __restrict__ klo,
    float* __restrict__ vb)
{
    const int z = blockIdx.z;
    const int rbase = blockIdx.y << 7;
    const int jbase = blockIdx.x << 7;
    const ushort* Ahi = xhi;
    const ushort* Alo = xhi;   // unused (TERMS=2)
    const ushort* Whi = whi + (size_t)z * 65536;
    const ushort* Wlo = wlo + (size_t)z * 65536;
    const float* bias = (z == 0) ? bq : (z == 1) ? bk : bv;
    GEMM_CORE(ND, 2)

    #pragma unroll
    for (int n = 0; n < 4; ++n) {
        const int cg = jbase + wc * 64 + n * 16 + col;
        const float bs = bias[cg];
        const int hh = cg >> 5, dd = cg & 31;
        #pragma unroll
        for (int m = 0; m < 4; ++m) {
            #pragma unroll
            for (int r = 0; r < 4; ++r) {
                const int row = rbase + wr * 64 + m * 16 + quad * 4 + r;
                const int b_i = row >> 10, s_i = row & 1023;
                size_t idx = (((size_t)(b_i * NH + hh)) * NS + s_i) * NDH + dd;
                float v = acc[m][n][r] + bs;
                if (z == 2) {
                    vb[idx] = v;
                } else if (z == 0) {
                    v = (v + hidden[idx]) * RSD;
                    ushort h = f2bf(v);
                    qhi[idx] = h;
                    qlo[idx] = f2bf(v - bf2f(h));
                } else {
                    ushort h = f2bf(v);
                    khi[idx] = h;
                    klo[idx] = f2bf(v - bf2f(h));
                }
            }
        }
    }
}

// ---------------------------------------------------------------------------
// O-proj + LN1 fused. Full-row tile: 64 rows x 256 cols, 4 waves x 16 rows.
// 3-term split MFMA. Epilogue: h = 2*(v+bo) -> hbuf fp32; LN1 stats fully
// in-register (sum over n, 4x shfl_xor over the 16 col-lanes); hn -> bf16.
// ---------------------------------------------------------------------------
__global__ __launch_bounds__(256, 2) void gemm_oproj_ln(
    const ushort* __restrict__ Ahi, const ushort* __restrict__ Alo,
    const ushort* __restrict__ Whi, const ushort* __restrict__ Wlo,
    const float* __restrict__ bias, const float* __restrict__ g,
    const float* __restrict__ be,
    float* __restrict__ hbuf, ushort* __restrict__ hnhi)
{
    __shared__ ushort sAh[64 * 40], sAl[64 * 40];
    __shared__ ushort sBh[256 * 40], sBl[256 * 40];
    const int t = threadIdx.x;
    const int w = t >> 6, ln = t & 63;
    const int col = ln & 15, quad = ln >> 4;
    const int rbase = blockIdx.x << 6;
    const int arow = t >> 2, akb = (t & 3) << 3;
    const ushort* gAh = Ahi + (size_t)(rbase + arow) * ND + akb;
    const ushort* gAl = Alo + (size_t)(rbase + arow) * ND + akb;
    const ushort* gBh = Whi + (size_t)t * ND;
    const ushort* gBl = Wlo + (size_t)t * ND;
    ushort* wAh = &sAh[arow * 40 + akb];
    ushort* wAl = &sAl[arow * 40 + akb];
    ushort* wBh = &sBh[t * 40];
    ushort* wBl = &sBl[t * 40];

    f32x4 acc[16] = {};
    short8 a0 = *(const short8*)gAh;
    short8 c0 = *(const short8*)gAl;
    short8 b0 = *(const short8*)(gBh),      b1 = *(const short8*)(gBh + 8);
    short8 b2v = *(const short8*)(gBh + 16), b3 = *(const short8*)(gBh + 24);
    short8 d0 = *(const short8*)(gBl),      d1 = *(const short8*)(gBl + 8);
    short8 d2v = *(const short8*)(gBl + 16), d3 = *(const short8*)(gBl + 24);

    for (int k0 = 0; k0 < ND; k0 += 32) {
        __syncthreads();
        *(short8*)wAh = a0; *(short8*)wAl = c0;
        *(short8*)(wBh + 0) = b0;  *(short8*)(wBh + 8) = b1;
        *(short8*)(wBh + 16) = b2v; *(short8*)(wBh + 24) = b3;
        *(short8*)(wBl + 0) = d0;  *(short8*)(wBl + 8) = d1;
        *(short8*)(wBl + 16) = d2v; *(short8*)(wBl + 24) = d3;
        __syncthreads();
        if (k0 + 32 < ND) {
            a0 = *(const short8*)(gAh + k0 + 32);
            c0 = *(const short8*)(gAl + k0 + 32);
            b0 = *(const short8*)(gBh + k0 + 32); b1 = *(const short8*)(gBh + k0 + 40);
            b2v = *(const short8*)(gBh + k0 + 48); b3 = *(const short8*)(gBh + k0 + 56);
            d0 = *(const short8*)(gBl + k0 + 32); d1 = *(const short8*)(gBl + k0 + 40);
            d2v = *(const short8*)(gBl + k0 + 48); d3 = *(const short8*)(gBl + k0 + 56);
        }
        short8 af  = *(const short8*)&sAh[(w * 16 + col) * 40 + quad * 8];
        short8 afl = *(const short8*)&sAl[(w * 16 + col) * 40 + quad * 8];
        #pragma unroll
        for (int n = 0; n < 16; ++n) {
            short8 bv = *(const short8*)&sBh[(n * 16 + col) * 40 + quad * 8];
            short8 bl = *(const short8*)&sBl[(n * 16 + col) * 40 + quad * 8];
            acc[n] = __builtin_amdgcn_mfma_f32_16x16x32_bf16(af,  bv, acc[n], 0, 0, 0);
            acc[n] = __builtin_amdgcn_mfma_f32_16x16x32_bf16(af,  bl, acc[n], 0, 0, 0);
            acc[n] = __builtin_amdgcn_mfma_f32_16x16x32_bf16(afl, bv, acc[n], 0, 0, 0);
        }
    }

    const int row0 = rbase + w * 16 + quad * 4;
    float s[4] = {}, s2[4] = {};
    #pragma unroll
    for (int n = 0; n < 16; ++n) {
        float bs = bias[n * 16 + col];
        #pragma unroll
        for (int r = 0; r < 4; ++r) {
            float hv = 2.f * (acc[n][r] + bs);
            acc[n][r] = hv;
            s[r] += hv; s2[r] += hv * hv;
            hbuf[(size_t)(row0 + r) * ND + n * 16 + col] = hv;
        }
    }
    float mu[4], rsd[4];
    #pragma unroll
    for (int r = 0; r < 4; ++r) {
        #pragma unroll
        for (int m = 8; m >= 1; m >>= 1) {
            s[r]  += __shfl_xor(s[r],  m, 64);
            s2[r] += __shfl_xor(s2[r], m, 64);
        }
        mu[r] = s[r] * (1.f / 256.f);
        float var = s2[r] * (1.f / 256.f) - mu[r] * mu[r];
        rsd[r] = rsqrtf(var + 1e-5f);
    }
    #pragma unroll
    for (int n = 0; n < 16; ++n) {
        float gv = g[n * 16 + col], bv = be[n * 16 + col];
        #pragma unroll
        for (int r = 0; r < 4; ++r)
            hnhi[(size_t)(row0 + r) * ND + n * 16 + col] =
                f2bf((acc[n][r] - mu[r]) * rsd[r] * gv + bv);
    }
}

// ---------------------------------------------------------------------------
// FFN2 + residual + LN2 fused. 64 rows x 256 cols, 2-term (ff-hi only).
// h = hbuf + (acc + b2); out = h + LN2(h). Eliminates ln_final.
// ---------------------------------------------------------------------------
__global__ __launch_bounds__(256, 2) void gemm_ffn2_ln(
    const ushort* __restrict__ Ahi,
    const ushort* __restrict__ Whi, const ushort* __restrict__ Wlo,
    const float* __restrict__ bias, const float* __restrict__ g,
    const float* __restrict__ be,
    const float* __restrict__ hbuf, float* __restrict__ out)
{
    __shared__ ushort sAh[64 * 40];
    __shared__ ushort sBh[256 * 40], sBl[256 * 40];
    const int t = threadIdx.x;
    const int w = t >> 6, ln = t & 63;
    const int col = ln & 15, quad = ln >> 4;
    const int rbase = blockIdx.x << 6;
    const int arow = t >> 2, akb = (t & 3) << 3;
    const ushort* gAh = Ahi + (size_t)(rbase + arow) * NF + akb;
    const ushort* gBh = Whi + (size_t)t * NF;
    const ushort* gBl = Wlo + (size_t)t * NF;
    ushort* wAh = &sAh[arow * 40 + akb];
    ushort* wBh = &sBh[t * 40];
    ushort* wBl = &sBl[t * 40];

    f32x4 acc[16] = {};
    short8 a0 = *(const short8*)gAh;
    short8 b0 = *(const short8*)(gBh),      b1 = *(const short8*)(gBh + 8);
    short8 b2v = *(const short8*)(gBh + 16), b3 = *(const short8*)(gBh + 24);
    short8 d0 = *(const short8*)(gBl),      d1 = *(const short8*)(gBl + 8);
    short8 d2v = *(const short8*)(gBl + 16), d3 = *(const short8*)(gBl + 24);

    for (int k0 = 0; k0 < NF; k0 += 32) {
        __syncthreads();
        *(short8*)wAh = a0;
        *(short8*)(wBh + 0) = b0;  *(short8*)(wBh + 8) = b1;
        *(short8*)(wBh + 16) = b2v; *(short8*)(wBh + 24) = b3;
        *(short8*)(wBl + 0) = d0;  *(short8*)(wBl + 8) = d1;
        *(short8*)(wBl + 16) = d2v; *(short8*)(wBl + 24) = d3;
        __syncthreads();
        if (k0 + 32 < NF) {
            a0 = *(const short8*)(gAh + k0 + 32);
            b0 = *(const short8*)(gBh + k0 + 32); b1 = *(const short8*)(gBh + k0 + 40);
            b2v = *(const short8*)(gBh + k0 + 48); b3 = *(const short8*)(gBh + k0 + 56);
            d0 = *(const short8*)(gBl + k0 + 32); d1 = *(const short8*)(gBl + k0 + 40);
            d2v = *(const short8*)(gBl + k0 + 48); d3 = *(const short8*)(gBl + k0 + 56);
        }
        short8 af = *(const short8*)&sAh[(w * 16 + col) * 40 + quad * 8];
        #pragma unroll
        for (int n = 0; n < 16; ++n) {
            short8 bv = *(const short8*)&sBh[(n * 16 + col) * 40 + quad * 8];
            short8 bl = *(const short8*)&sBl[(n * 16 + col) * 40 + quad * 8];
            acc[n] = __builtin_amdgcn_mfma_f32_16x16x32_bf16(af, bv, acc[n], 0, 0, 0);
            acc[n] = __builtin_amdgcn_mfma_f32_16x16x32_bf16(af, bl, acc[n], 0, 0, 0);
        }
    }

    const int row0 = rbase + w * 16 + quad * 4;
    float s[4] = {}, s2[4] = {};
    #pragma unroll
    for (int n = 0; n < 16; ++n) {
        float bs = bias[n * 16 + col];
        #pragma unroll
        for (int r = 0; r < 4; ++r) {
            float hv = hbuf[(size_t)(row0 + r) * ND + n * 16 + col] + acc[n][r] + bs;
            acc[n][r] = hv;
            s[r] += hv; s2[r] += hv * hv;
        }
    }
    float mu[4], rsd[4];
    #pragma unroll
    for (int r = 0; r < 4; ++r) {
        #pragma unroll
        for (int m = 8; m >= 1; m >>= 1) {
            s[r]  += __shfl_xor(s[r],  m, 64);
            s2[r] += __shfl_xor(s2[r], m, 64);
        }
        mu[r] = s[r] * (1.f / 256.f);
        float var = s2[r] * (1.f / 256.f) - mu[r] * mu[r];
        rsd[r] = rsqrtf(var + 1e-5f);
    }
    #pragma unroll
    for (int n = 0; n < 16; ++n) {
        float gv = g[n * 16 + col], bv = be[n * 16 + col];
        #pragma unroll
        for (int r = 0; r < 4; ++r) {
            float hv = acc[n][r];
            out[(size_t)(row0 + r) * ND + n * 16 + col] =
                hv + (hv - mu[r]) * rsd[r] * gv + bv;
        }
    }
}

// ---------------------------------------------------------------------------
// Flash-fused attention (R10-measured). Block = 4 waves = 64 q-rows of one bh.
// ---------------------------------------------------------------------------
constexpr int VS  = 136;
constexpr int PST = 136;
__global__ __launch_bounds__(256, 4) void attn_flash(
    const ushort* __restrict__ qhi, const ushort* __restrict__ qlo,
    const ushort* __restrict__ khi, const ushort* __restrict__ klo,
    const float* __restrict__ vb,
    float* __restrict__ attn, ushort* __restrict__ cthi, ushort* __restrict__ ctlo)
{
    __shared__ ushort Vthi[32 * VS];
    __shared__ ushort Vtlo[32 * VS];
    __shared__ ushort Ps[4][16 * PST];
    const int bid = blockIdx.x;
    const int lid = (bid & 7) * 512 + (bid >> 3);   // 4096 % 8 == 0: bijective
    const int qt = lid & 15, bh = lid >> 4;
    const int q0 = qt << 6;
    const int t = threadIdx.x;
    const int w = t >> 6, ln = t & 63;
    const int col = ln & 15, quad = ln >> 4;
    const int qr0 = q0 + 16 * w;
    ushort* myP = Ps[w];

    const size_t bhbase = (size_t)bh * NS * NDH;
    const size_t aoff = bhbase + (size_t)(qr0 + col) * NDH + quad * 8;
    const short8 ahi = *(const short8*)(qhi + aoff);
    const short8 alo = *(const short8*)(qlo + aoff);

    const float* vbase = vb + bhbase;
    const int sdd = t & 31, skg = (t >> 5) << 4;

    f32x4 acc0 = {0.f, 0.f, 0.f, 0.f}, acc1 = {0.f, 0.f, 0.f, 0.f};
    float S[4] = {0.f, 0.f, 0.f, 0.f};

    // ================= Pass 1 =================
    for (int k0 = 0; k0 < NS; k0 += 128) {
        __syncthreads();
        ushort hs[16], ls[16];
        #pragma unroll
        for (int c = 0; c < 16; ++c) {
            float xx = vbase[(size_t)(k0 + skg + c) * NDH + sdd];
            ushort h = f2bf(xx);
            hs[c] = h; ls[c] = f2bf(xx - bf2f(h));
        }
        #pragma unroll
        for (int c4 = 0; c4 < 4; ++c4) {
            ushort4 hv = make_ushort4(hs[c4 * 4], hs[c4 * 4 + 1], hs[c4 * 4 + 2], hs[c4 * 4 + 3]);
            ushort4 lv = make_ushort4(ls[c4 * 4], ls[c4 * 4 + 1], ls[c4 * 4 + 2], ls[c4 * 4 + 3]);
            *(ushort4*)&Vthi[sdd * VS + skg + c4 * 4] = hv;
            *(ushort4*)&Vtlo[sdd * VS + skg + c4 * 4] = lv;
        }
        __syncthreads();

        #pragma unroll
        for (int tl = 0; tl < 8; ++tl) {
            const int kk = k0 + tl * 16;
            const size_t boff = bhbase + (size_t)(kk + col) * NDH + quad * 8;
            short8 bhi = *(const short8*)(khi + boff);
            short8 blo = *(const short8*)(klo + boff);
            f32x4 c = {0.f, 0.f, 0.f, 0.f};
            c = __builtin_amdgcn_mfma_f32_16x16x32_bf16(ahi, bhi, c, 0, 0, 0);
            c = __builtin_amdgcn_mfma_f32_16x16x32_bf16(ahi, blo, c, 0, 0, 0);
            c = __builtin_amdgcn_mfma_f32_16x16x32_bf16(alo, bhi, c, 0, 0, 0);
            #pragma unroll
            for (int r = 0; r < 4; ++r) {
                float e = __expf(c[r]);
                S[r] += e;
                myP[(quad * 4 + r) * PST + tl * 16 + col] = f2bf(e);
            }
        }

        #pragma unroll
        for (int sl = 0; sl < 4; ++sl) {
            const int kl = sl * 32 + quad * 8;
            short8 pa = *(const short8*)&myP[col * PST + kl];
            short8 bhi0 = *(const short8*)&Vthi[col * VS + kl];
            short8 blo0 = *(const short8*)&Vtlo[col * VS + kl];
            short8 bhi1 = *(const short8*)&Vthi[(16 + col) * VS + kl];
            short8 blo1 = *(const short8*)&Vtlo[(16 + col) * VS + kl];
            acc0 = __builtin_amdgcn_mfma_f32_16x16x32_bf16(pa, bhi0, acc0, 0, 0, 0);
            acc0 = __builtin_amdgcn_mfma_f32_16x16x32_bf16(pa, blo0, acc0, 0, 0, 0);
            acc1 = __builtin_amdgcn_mfma_f32_16x16x32_bf16(pa, bhi1, acc1, 0, 0, 0);
            acc1 = __builtin_amdgcn_mfma_f32_16x16x32_bf16(pa, blo1, acc1, 0, 0, 0);
        }
    }

    float inv[4];
    #pragma unroll
    for (int r = 0; r < 4; ++r) {
        float s = S[r];
        #pragma unroll
        for (int m = 8; m >= 1; m >>= 1) s += __shfl_xor(s, m, 64);
        inv[r] = 1.f / s;
    }

    const int b_i = bh >> 3, hh = bh & 7;
    const int qrow = qr0 + quad * 4;
    #pragma unroll
    for (int r = 0; r < 4; ++r) {
        size_t base = ((size_t)b_i * NS + qrow + r) * ND + hh * NDH;
        float v0 = acc0[r] * inv[r], v1 = acc1[r] * inv[r];
        ushort h0 = f2bf(v0), h1 = f2bf(v1);
        cthi[base + col]      = h0;
        ctlo[base + col]      = f2bf(v0 - bf2f(h0));
        cthi[base + 16 + col] = h1;
        ctlo[base + 16 + col] = f2bf(v1 - bf2f(h1));
    }

    // ================= Pass 2: attn output =================
    float* abase = attn + ((size_t)bh * NS + qrow) * NS;
    #pragma unroll 4
    for (int tl = 0; tl < 64; ++tl) {
        const int kk = tl * 16;
        const size_t boff = bhbase + (size_t)(kk + col) * NDH + quad * 8;
        short8 bhi = *(const short8*)(khi + boff);
        short8 blo = *(const short8*)(klo + boff);
        f32x4 c = {0.f, 0.f, 0.f, 0.f};
        c = __builtin_amdgcn_mfma_f32_16x16x32_bf16(ahi, bhi, c, 0, 0, 0);
        c = __builtin_amdgcn_mfma_f32_16x16x32_bf16(ahi, blo, c, 0, 0, 0);
        c = __builtin_amdgcn_mfma_f32_16x16x32_bf16(alo, bhi, c, 0, 0, 0);
        #pragma unroll
        for (int r = 0; r < 4; ++r) {
            float p = __expf(c[r]) * inv[r];
            __builtin_nontemporal_store(p, &abase[(size_t)r * NS + kk + col]);
        }
    }
}

// ---------------------------------------------------------------------------
extern "C" void kernel_launch(void* const* d_in, const int* in_sizes, int n_in,
                              void* d_out, int out_size, void* d_ws, size_t ws_size,
                              hipStream_t stream)
{
    const float* x      = (const float*)d_in[0];
    const float* hidden = (const float*)d_in[1];
    const float* Wq = (const float*)d_in[2];
    const float* bq = (const float*)d_in[3];
    const float* Wk = (const float*)d_in[4];
    const float* bk = (const float*)d_in[5];
    const float* Wv = (const float*)d_in[6];
    const float* bv = (const float*)d_in[7];
    const float* Wo = (const float*)d_in[8];
    const float* bo = (const float*)d_in[9];
    const float* g1  = (const float*)d_in[10];
    const float* be1 = (const float*)d_in[11];
    const float* g2  = (const float*)d_in[12];
    const float* be2 = (const float*)d_in[13];
    const float* W1 = (const float*)d_in[14];
    const float* b1 = (const float*)d_in[15];
    const float* W2 = (const float*)d_in[16];
    const float* b2 = (const float*)d_in[17];

    float* out  = (float*)d_out;
    float* attn = out + (size_t)NM * ND;

    float* ws = (float*)d_ws;
    ushort* xhi  = (ushort*)ws;
    ushort* qhi  = (ushort*)(ws + 8388608);
    ushort* qlo  = (ushort*)(ws + 12582912);
    ushort* khi  = (ushort*)(ws + 16777216);
    ushort* klo  = (ushort*)(ws + 20971520);
    float*  vbuf = ws + 25165824;                 // fp32 [B,H,S,32]
    ushort* cthi = (ushort*)ws;                   // reuse x region
    ushort* ctlo = (ushort*)(ws + 4194304);
    float*  hbuf = ws + 33554432;                 // fp32 [M,256]
    ushort* hnhi = (ushort*)(ws + 8388608);       // reuse q region
    ushort* ffhi = (ushort*)(ws + 16777216);      // reuse k region
    ushort* whi  = (ushort*)(ws + 41943040);
    ushort* wlo  = (ushort*)(ws + 42205184);

    split_weights<<<dim3(128, 6), 256, 0, stream>>>(Wq, Wk, Wv, Wo, W1, W2, whi, wlo);
    split_hi<<<8192, 256, 0, stream>>>(x, xhi, 2097152);

    // 1. QKV projections (2-term: x-hi only)
    gemm_qkv_mfma<<<dim3(2, 256, 3), 256, 0, stream>>>(
        xhi, whi, wlo, bq, bk, bv, hidden, qhi, qlo, khi, klo, vbuf);
    // 2+3. flash-fused scores+softmax+PV; writes attn + ctx
    attn_flash<<<dim3(4096), 256, 0, stream>>>(
        qhi, qlo, khi, klo, vbuf, attn, cthi, ctlo);
    // 4+5. h = 2*(ctx @ Wo.T + bo) -> hbuf; hn = LN1(h) -> hnhi  (fused)
    gemm_oproj_ln<<<dim3(NM / 64), 256, 0, stream>>>(
        cthi, ctlo, whi + 196608, wlo + 196608, bo, g1, be1, hbuf, hnhi);
    // 6. ff = relu(hn @ W1.T + b1) -> bf16 hi only (2-term)
    gemm_mfma<2><<<dim3(4, 256), 256, 0, stream>>>(
        hnhi, nullptr, whi + 262144, wlo + 262144, b1, nullptr, ffhi, NF, ND, 1);
    // 7+8. h += ff @ W2.T + b2; out = h + LN2(h)  (fused)
    gemm_ffn2_ln<<<dim3(NM / 64), 256, 0, stream>>>(
        ffhi, whi + 393216, wlo + 393216, b2, g2, be2, hbuf, out);
}